// Round 6
// baseline (345.415 us; speedup 1.0000x reference)
//
#include <hip/hip_runtime.h>

#define DD 256
#define HH 512
#define BB 128
#define TS 4096                      // floats per tape step block (16 KB)
#define APOFF (255 * TS + 2048)      // appendix (W1 rows 510/511) inside block 255's unused tail

#define WAITVM(N) asm volatile("s_waitcnt vmcnt(" #N ")" ::: "memory")

__device__ __forceinline__ float elu_f(float x) {
    return x > 0.f ? x : (__expf(x) - 1.f);
}

__device__ __forceinline__ float bcast(float v, int l) {
    return __uint_as_float(__builtin_amdgcn_readlane(__float_as_uint(v), (unsigned)l));
}

template <int CTRL, int RM>
__device__ __forceinline__ float dpp_add(float x) {
    int t = __builtin_amdgcn_update_dpp(0, __float_as_int(x), CTRL, RM, 0xf, true);
    return x + __int_as_float(t);
}

// full wave64 sum, all-VALU (verified numerically in round 5)
__device__ __forceinline__ float wave_reduce(float v) {
    v = dpp_add<0xB1, 0xf>(v);
    v = dpp_add<0x4E, 0xf>(v);
    v = dpp_add<0x141, 0xf>(v);
    v = dpp_add<0x140, 0xf>(v);
    v = dpp_add<0x142, 0xa>(v);
    v = dpp_add<0x143, 0xc>(v);
    return bcast(v, 63);
}

__device__ __forceinline__ float sel8(const float (&a)[8], int e) {
    float v = a[0];
    #pragma unroll
    for (int k = 1; k < 8; ++k) v = (e == k) ? a[k] : v;
    return v;
}

__device__ __forceinline__ float dot8(const float4& w0, const float4& w1, const float (&h)[8]) {
    float p0 = w0.x*h[0] + w0.y*h[1];
    float p1 = w0.z*h[2] + w0.w*h[3];
    float p2 = w1.x*h[4] + w1.y*h[5];
    float p3 = w1.z*h[6] + w1.w*h[7];
    return (p0 + p1) + (p2 + p3);
}

__device__ __forceinline__ void axpy8(float (&a)[8], const float4& w0, const float4& w1, float v) {
    a[0] += v*w0.x; a[1] += v*w0.y; a[2] += v*w0.z; a[3] += v*w0.w;
    a[4] += v*w1.x; a[5] += v*w1.y; a[6] += v*w1.z; a[7] += v*w1.w;
}

__device__ __forceinline__ void push2(float (&a)[8], const float4& wA0, const float4& wA1,
                                      const float4& wB0, const float4& wB1, float p0, float p1) {
    a[0] += wA0.x*p0 + wB0.x*p1; a[1] += wA0.y*p0 + wB0.y*p1;
    a[2] += wA0.z*p0 + wB0.z*p1; a[3] += wA0.w*p0 + wB0.w*p1;
    a[4] += wA1.x*p0 + wB1.x*p1; a[5] += wA1.y*p0 + wB1.y*p1;
    a[6] += wA1.z*p0 + wB1.z*p1; a[7] += wA1.w*p0 + wB1.w*p1;
}

__device__ __forceinline__ void push1(float (&a)[8], const float4& w0, const float4& w1, float p) {
    a[0] += w0.x*p; a[1] += w0.y*p; a[2] += w0.z*p; a[3] += w0.w*p;
    a[4] += w1.x*p; a[5] += w1.y*p; a[6] += w1.z*p; a[7] += w1.w*p;
}

// async DMA of one 16 KB tape block into an LDS slot: 16 × (64 lanes × 16 B)
__device__ __forceinline__ void dma16(const float* __restrict__ src, float* dst, int lane) {
    const float* s = src + lane * 4;
    #pragma unroll
    for (int k = 0; k < 16; ++k) {
        __builtin_amdgcn_global_load_lds(
            (const __attribute__((address_space(1))) void*)(s + k * 256),
            (__attribute__((address_space(3))) void*)(dst + k * 256),
            16, 0, 0);
    }
}

// =========================== prep: build the tape ===========================
// tape block i (4096 floats): [0]Wo_m[i] [512]Wo_l[i] [1024]W0T_m[i] [1536]W0T_l[i]
//                             [2048]W1T_m[i] [2560]W1T_l[i] [3072]W1T_m[i+255] [3584]W1T_l[i+255]
// appendix at APOFF: [W1T_m[510], W1T_l[510], W1T_m[511], W1T_l[511]]
__global__ __launch_bounds__(256) void prep_t(
    const float* __restrict__ w0m_, const float* __restrict__ w0l_,
    const float* __restrict__ w1m_, const float* __restrict__ w1l_,
    const float* __restrict__ wom_, const float* __restrict__ wol_,
    float* __restrict__ tape)
{
    __shared__ float tm[32][33], tl[32][33];
    const int tx = threadIdx.x & 31, ty = threadIdx.x >> 5;
    const unsigned b = blockIdx.x;

    if (b < 256) {                              // W1 transpose+mask (512x512)
        const int by = b >> 4, bx = b & 15;
        const int r0 = by << 5, c0 = bx << 5;   // r = h (row of W1), c = hp (col)
        #pragma unroll
        for (int j = 0; j < 4; ++j) {
            int r = r0 + ty + 8 * j;
            tm[ty + 8 * j][tx] = w1m_[r * HH + c0 + tx];
            tl[ty + 8 * j][tx] = w1l_[r * HH + c0 + tx];
        }
        __syncthreads();
        #pragma unroll
        for (int j = 0; j < 4; ++j) {
            int c = c0 + ty + 8 * j;
            int r = r0 + tx;
            float mask = ((r % 255) >= (c % 255)) ? 1.f : 0.f;
            int base;
            if (c <= 254)      base = c * TS + 2048;
            else if (c <= 509) base = (c - 255) * TS + 3072;
            else               base = APOFF + (c - 510) * 1024;
            tape[base + r]       = mask * tm[tx][ty + 8 * j];
            tape[base + 512 + r] = mask * tl[tx][ty + 8 * j];
        }
    } else if (b < 384) {                       // W0 transpose (512x256)
        const int b2 = b - 256;
        const int by = b2 >> 3, bx = b2 & 7;
        const int r0 = by << 5, c0 = bx << 5;   // r = h, c = i
        #pragma unroll
        for (int j = 0; j < 4; ++j) {
            int r = r0 + ty + 8 * j;
            tm[ty + 8 * j][tx] = w0m_[r * DD + c0 + tx];
            tl[ty + 8 * j][tx] = w0l_[r * DD + c0 + tx];
        }
        __syncthreads();
        #pragma unroll
        for (int j = 0; j < 4; ++j) {
            int c = c0 + ty + 8 * j;
            int r = r0 + tx;
            tape[c * TS + 1024 + r] = tm[tx][ty + 8 * j];
            tape[c * TS + 1536 + r] = tl[tx][ty + 8 * j];
        }
    } else {                                    // Wo copy (256x512), coalesced
        int base_t = (b - 384) * 512 + threadIdx.x;
        #pragma unroll
        for (int k = 0; k < 2; ++k) {
            int t2 = base_t + k * 256;          // 0..131071
            int i = t2 >> 9, h = t2 & 511;
            tape[i * TS + h]       = wom_[t2];
            tape[i * TS + 512 + h] = wol_[t2];
        }
    }
}

// =============================== main kernel ===============================
__device__ __forceinline__ void step_fin(
    int i, const int (&fin)[8],
    float (&a1m)[8], float (&a1l)[8], float (&h1m)[8], float (&h1l)[8])
{
    #pragma unroll
    for (int e = 0; e < 8; ++e) {
        if (fin[e] == i) {
            h1m[e] = elu_f(a1m[e]);
            h1l[e] = elu_f(a1l[e]);
        }
    }
}

__device__ __forceinline__ void step_compute(
    int i, const float4* s4, int lane,
    const float* x_s, const float* bom_s, const float* bol_s, float* y_s,
    float (&a0m)[8], float (&a0l)[8], float (&a1m)[8], float (&a1l)[8],
    float (&h1m)[8], float (&h1l)[8], float& ls_sum, bool do_fin)
{
    float4 wm0 = s4[lane],       wm1 = s4[64 + lane];
    float4 wl0 = s4[128 + lane], wl1 = s4[192 + lane];
    float accm = wave_reduce(dot8(wm0, wm1, h1m));
    float accl = wave_reduce(dot8(wl0, wl1, h1l));
    float mu = accm + bom_s[i];
    float ls = 0.5f * (accl + bol_s[i]);
    ls_sum += ls;
    float v = __fdividef(x_s[i] - mu, __expf(ls) + 1e-12f);
    if (lane == 0) y_s[i] = v;

    float4 w0m0 = s4[256 + lane], w0m1 = s4[320 + lane];
    float4 w0l0 = s4[384 + lane], w0l1 = s4[448 + lane];
    axpy8(a0m, w0m0, w0m1, v);
    axpy8(a0l, w0l0, w0l1, v);

    if (do_fin) {
        int e0 = i & 3, l0 = i >> 2;
        float p0m = elu_f(bcast(sel8(a0m, e0), l0));
        float p0l = elu_f(bcast(sel8(a0l, e0), l0));
        int hp1 = i + 255;
        int e1 = 4 * (hp1 >> 8) + (hp1 & 3);
        int l1 = (hp1 & 255) >> 2;
        float p1m = elu_f(bcast(sel8(a0m, e1), l1));
        float p1l = elu_f(bcast(sel8(a0l, e1), l1));
        float4 wa0  = s4[512 + lane], wa1  = s4[576 + lane];
        float4 wal0 = s4[640 + lane], wal1 = s4[704 + lane];
        float4 wb0  = s4[768 + lane], wb1  = s4[832 + lane];
        float4 wbl0 = s4[896 + lane], wbl1 = s4[960 + lane];
        push2(a1m, wa0, wa1, wb0, wb1, p0m, p1m);
        push2(a1l, wal0, wal1, wbl0, wbl1, p0l, p1l);
    }
}

__global__ __launch_bounds__(64, 1) void made_main(
    const float* __restrict__ x,
    const float* __restrict__ mu_b0, const float* __restrict__ mu_b1,
    const float* __restrict__ mu_bo,
    const float* __restrict__ lv_b0, const float* __restrict__ lv_b1,
    const float* __restrict__ lv_bo,
    const float* __restrict__ tape,
    float* __restrict__ out)
{
    __shared__ __align__(16) float slot0[TS], slot1[TS], slot2[TS];
    __shared__ __align__(16) float x_s[DD], bom_s[DD], bol_s[DD], y_s[DD];

    const int lane = threadIdx.x;
    const int row  = blockIdx.x;

    float a0m[8], a0l[8], a1m[8], a1l[8], h1m[8], h1l[8];
    int fin[8];
    {
        float4 t0, t1;
        t0 = ((const float4*)mu_b0)[lane]; t1 = ((const float4*)mu_b0)[64 + lane];
        a0m[0]=t0.x; a0m[1]=t0.y; a0m[2]=t0.z; a0m[3]=t0.w;
        a0m[4]=t1.x; a0m[5]=t1.y; a0m[6]=t1.z; a0m[7]=t1.w;
        t0 = ((const float4*)lv_b0)[lane]; t1 = ((const float4*)lv_b0)[64 + lane];
        a0l[0]=t0.x; a0l[1]=t0.y; a0l[2]=t0.z; a0l[3]=t0.w;
        a0l[4]=t1.x; a0l[5]=t1.y; a0l[6]=t1.z; a0l[7]=t1.w;
        t0 = ((const float4*)mu_b1)[lane]; t1 = ((const float4*)mu_b1)[64 + lane];
        a1m[0]=t0.x; a1m[1]=t0.y; a1m[2]=t0.z; a1m[3]=t0.w;
        a1m[4]=t1.x; a1m[5]=t1.y; a1m[6]=t1.z; a1m[7]=t1.w;
        t0 = ((const float4*)lv_b1)[lane]; t1 = ((const float4*)lv_b1)[64 + lane];
        a1l[0]=t0.x; a1l[1]=t0.y; a1l[2]=t0.z; a1l[3]=t0.w;
        a1l[4]=t1.x; a1l[5]=t1.y; a1l[6]=t1.z; a1l[7]=t1.w;
    }
    #pragma unroll
    for (int e = 0; e < 8; ++e) {
        h1m[e] = 0.f; h1l[e] = 0.f;
        int h = (e >> 2) * 256 + 4 * lane + (e & 3);
        fin[e] = h % 255;
    }
    ((float4*)x_s)[lane]   = ((const float4*)(x + row * DD))[lane];
    ((float4*)bom_s)[lane] = ((const float4*)mu_bo)[lane];
    ((float4*)bol_s)[lane] = ((const float4*)lv_bo)[lane];
    __syncthreads();

    // E rows (W1T 510/511) as regular register loads — consumed at steps 0/1
    const float* ap = tape + APOFF;
    float4 E0m0 = ((const float4*)(ap))[lane],        E0m1 = ((const float4*)(ap))[64 + lane];
    float4 E0l0 = ((const float4*)(ap + 512))[lane],  E0l1 = ((const float4*)(ap + 512))[64 + lane];
    float4 E1m0 = ((const float4*)(ap + 1024))[lane], E1m1 = ((const float4*)(ap + 1024))[64 + lane];
    float4 E1l0 = ((const float4*)(ap + 1536))[lane], E1l1 = ((const float4*)(ap + 1536))[64 + lane];

    // prefill ring: steps 0,1
    dma16(tape + 0 * TS, slot0, lane);
    dma16(tape + 1 * TS, slot1, lane);

    float ls_sum = 0.f;

    // ---- step 0 (slot0; extra finalizer h=510 via E0) ----
    dma16(tape + 2 * TS, slot2, lane);
    WAITVM(32);
    step_compute(0, (const float4*)slot0, lane, x_s, bom_s, bol_s, y_s,
                 a0m, a0l, a1m, a1l, h1m, h1l, ls_sum, true);
    {
        float pm = elu_f(bcast(sel8(a0m, 6), 63));
        float pl = elu_f(bcast(sel8(a0l, 6), 63));
        push1(a1m, E0m0, E0m1, pm);
        push1(a1l, E0l0, E0l1, pl);
    }
    step_fin(0, fin, a1m, a1l, h1m, h1l);

    // ---- step 1 (slot1; extra finalizer h=511 via E1) ----
    dma16(tape + 3 * TS, slot0, lane);
    WAITVM(32);
    step_compute(1, (const float4*)slot1, lane, x_s, bom_s, bol_s, y_s,
                 a0m, a0l, a1m, a1l, h1m, h1l, ls_sum, true);
    {
        float pm = elu_f(bcast(sel8(a0m, 7), 63));
        float pl = elu_f(bcast(sel8(a0l, 7), 63));
        push1(a1m, E1m0, E1m1, pm);
        push1(a1l, E1l0, E1l1, pl);
    }
    step_fin(1, fin, a1m, a1l, h1m, h1l);

    // ---- steps 2..253: 3-slot ring, dma(i+2) then wait vmcnt(32) ----
    #pragma unroll 1
    for (int t = 0; t < 84; ++t) {
        int i = 3 * t + 2;
        dma16(tape + (size_t)(i + 2) * TS, slot1, lane);
        WAITVM(32);
        step_compute(i, (const float4*)slot2, lane, x_s, bom_s, bol_s, y_s,
                     a0m, a0l, a1m, a1l, h1m, h1l, ls_sum, true);
        step_fin(i, fin, a1m, a1l, h1m, h1l);

        dma16(tape + (size_t)(i + 3) * TS, slot2, lane);
        WAITVM(32);
        step_compute(i + 1, (const float4*)slot0, lane, x_s, bom_s, bol_s, y_s,
                     a0m, a0l, a1m, a1l, h1m, h1l, ls_sum, true);
        step_fin(i + 1, fin, a1m, a1l, h1m, h1l);

        dma16(tape + (size_t)(i + 4) * TS, slot0, lane);
        WAITVM(32);
        step_compute(i + 2, (const float4*)slot1, lane, x_s, bom_s, bol_s, y_s,
                     a0m, a0l, a1m, a1l, h1m, h1l, ls_sum, true);
        step_fin(i + 2, fin, a1m, a1l, h1m, h1l);
    }

    // ---- step 254 (slot2), no more dma ----
    WAITVM(16);
    step_compute(254, (const float4*)slot2, lane, x_s, bom_s, bol_s, y_s,
                 a0m, a0l, a1m, a1l, h1m, h1l, ls_sum, true);
    step_fin(254, fin, a1m, a1l, h1m, h1l);

    // ---- step 255 (slot0): output only ----
    WAITVM(0);
    {
        const float4* s4 = (const float4*)slot0;
        float4 wm0 = s4[lane],       wm1 = s4[64 + lane];
        float4 wl0 = s4[128 + lane], wl1 = s4[192 + lane];
        float accm = wave_reduce(dot8(wm0, wm1, h1m));
        float accl = wave_reduce(dot8(wl0, wl1, h1l));
        float mu = accm + bom_s[255];
        float ls = 0.5f * (accl + bol_s[255]);
        ls_sum += ls;
        float v = __fdividef(x_s[255] - mu, __expf(ls) + 1e-12f);
        if (lane == 0) y_s[255] = v;
    }

    __syncthreads();
    ((float4*)(out + row * DD))[lane] = ((const float4*)y_s)[lane];
    if (lane == 0) out[BB * DD + row] = ls_sum;
}

extern "C" void kernel_launch(void* const* d_in, const int* in_sizes, int n_in,
                              void* d_out, int out_size, void* d_ws, size_t ws_size,
                              hipStream_t stream) {
    const float* x     = (const float*)d_in[0];
    const float* mu_W0 = (const float*)d_in[1];
    const float* mu_b0 = (const float*)d_in[2];
    const float* mu_W1 = (const float*)d_in[3];
    const float* mu_b1 = (const float*)d_in[4];
    const float* mu_Wo = (const float*)d_in[5];
    const float* mu_bo = (const float*)d_in[6];
    const float* lv_W0 = (const float*)d_in[7];
    const float* lv_b0 = (const float*)d_in[8];
    const float* lv_W1 = (const float*)d_in[9];
    const float* lv_b1 = (const float*)d_in[10];
    const float* lv_Wo = (const float*)d_in[11];
    const float* lv_bo = (const float*)d_in[12];

    float* tape = (float*)d_ws;   // exactly 4 MiB

    prep_t<<<640, 256, 0, stream>>>(mu_W0, lv_W0, mu_W1, lv_W1, mu_Wo, lv_Wo, tape);
    made_main<<<BB, 64, 0, stream>>>(x, mu_b0, mu_b1, mu_bo,
                                     lv_b0, lv_b1, lv_bo, tape, (float*)d_out);
}

// Round 7
// 284.658 us; speedup vs baseline: 1.2134x; 1.2134x over previous
//
#include <hip/hip_runtime.h>

#define DD 256
#define HH 512
#define BB 128
#define TS 4096   // floats per tape block (16 KB)

#define WAITVM(N) asm volatile("s_waitcnt vmcnt(" #N ")" ::: "memory")

__device__ __forceinline__ float elu_f(float x) {
    return x > 0.f ? x : (__expf(x) - 1.f);
}
__device__ __forceinline__ float rlf(float v, int l) {
    return __uint_as_float(__builtin_amdgcn_readlane(__float_as_uint(v), (unsigned)l));
}
__device__ __forceinline__ float f4c(const float4& v, int r) {
    return r == 0 ? v.x : r == 1 ? v.y : r == 2 ? v.z : v.w;
}
__device__ __forceinline__ void dma16(const float* __restrict__ src, float* dst, int lane) {
    const float* s = src + lane * 4;
    #pragma unroll
    for (int k = 0; k < 16; ++k) {
        __builtin_amdgcn_global_load_lds(
            (const __attribute__((address_space(1))) void*)(s + k * 256),
            (__attribute__((address_space(3))) void*)(dst + k * 256),
            16, 0, 0);
    }
}

// Unit slot map: lane L, A-reg r (0..3) <-> h = L+64r  [exception (63,3) -> h=510]
//                lane L, B-reg 4+r     <-> h = 255+L+64r [exception (63,3) -> h=511]
// Unit h finalizes at step: A: L+64r (=h); B: L+64r (=h-255); 510->step0, 511->step1.
// Column j <-> lane j&63, reg j>>6 (R accumulators, 4/lane).
//
// Tape block i (4096 floats), all rows packed per-lane [pos = fam*256 + 4L + r]:
//  [0]    W1T[i]     m   [512]  W1T[i]     l
//  [1024] W1T[i+255] m   [1536] W1T[i+255] l
//  [2048] W0T[i]     m   [2560] W0T[i]     l
//  [3072] WoT[i]     m   [3328] WoT[i]     l     (256 floats, pos=4L+r, j=L+64r)
//  [3584] WoT[i+255] m   [3840] WoT[i+255] l
// Block 255 = appendix: [0/512] W1T[510] m/l, [1024/1536] W1T[511] m/l,
//  [2048/2304] WoT[510] m/l, [2560/2816] WoT[511] m/l.
__global__ __launch_bounds__(256) void prep(
    const float* __restrict__ w0m_, const float* __restrict__ w0l_,
    const float* __restrict__ w1m_, const float* __restrict__ w1l_,
    const float* __restrict__ wom_, const float* __restrict__ wol_,
    float* __restrict__ tape)
{
    int t = blockIdx.x * 256 + threadIdx.x;     // < 523776
    if (t < 262144) {                           // W1T rows (hp = W1 column)
        int hp = t >> 9, p = t & 511;
        int fam = p >> 8, L = (p & 255) >> 2, r = p & 3;
        int h = (L == 63 && r == 3) ? (fam ? 511 : 510)
                                    : (fam ? 255 + L + 64 * r : L + 64 * r);
        int dh_h = (h <= 254) ? h + 1 : (h <= 509 ? h - 254 : h - 509);
        int dh_p = (hp <= 254) ? hp + 1 : (hp <= 509 ? hp - 254 : hp - 509);
        bool msk = dh_h >= dh_p;
        float vm = msk ? w1m_[h * HH + hp] : 0.f;
        float vl = msk ? w1l_[h * HH + hp] : 0.f;
        int base = (hp <= 254) ? hp * TS
                 : (hp <= 509) ? (hp - 255) * TS + 1024
                 : 255 * TS + (hp == 510 ? 0 : 1024);
        tape[base + p]       = vm;
        tape[base + 512 + p] = vl;
    } else if (t < 392704) {                    // W0T rows i=0..254
        int u = t - 262144;
        int i = u >> 9, p = u & 511;
        int fam = p >> 8, L = (p & 255) >> 2, r = p & 3;
        int h = (L == 63 && r == 3) ? (fam ? 511 : 510)
                                    : (fam ? 255 + L + 64 * r : L + 64 * r);
        tape[i * TS + 2048 + p] = w0m_[h * DD + i];
        tape[i * TS + 2560 + p] = w0l_[h * DD + i];
    } else {                                    // WoT rows (hp = Wo column)
        int u = t - 392704;
        int hp = u >> 8, p = u & 255;
        int L = p >> 2, r = p & 3;
        int j = L + 64 * r;
        int base = (hp <= 254) ? hp * TS + 3072
                 : (hp <= 509) ? (hp - 255) * TS + 3584
                 : 255 * TS + (hp == 510 ? 2048 : 2560);
        tape[base + p]       = wom_[j * HH + hp];
        tape[base + 256 + p] = wol_[j * HH + hp];
    }
}

// ================================ main =====================================
template<int Q, int EX>
__device__ __forceinline__ void stepT(
    int i, int t, int lane, const float4* __restrict__ s4, float* __restrict__ y_s,
    float (&a0m)[8], float (&a0l)[8], float (&a1m)[8], float (&a1l)[8],
    float (&Rm)[4], float (&Rl)[4],
    const float (&xv)[4], const float (&bmv)[4], const float (&blv)[4],
    float& ls_sum,
    const float4& exmA, const float4& exmB, const float4& exlA, const float4& exlB,
    const float4& exwm, const float4& exwl)
{
    // ---- output column i: mu/ls are readlanes of the incremental accumulator ----
    float mu = rlf(Rm[Q], t) + rlf(bmv[Q], t);
    float ls = 0.5f * (rlf(Rl[Q], t) + rlf(blv[Q], t));
    ls_sum += ls;
    float v = __fdividef(rlf(xv[Q], t) - mu, __expf(ls) + 1e-12f);
    if (lane == 0) y_s[i] = v;

    // ---- a0 += v * W0T[i] (live regs r>=Q only) ----
    float4 w0mA = s4[512 + lane], w0mB = s4[576 + lane];
    float4 w0lA = s4[640 + lane], w0lB = s4[704 + lane];
    #pragma unroll
    for (int r = Q; r < 4; ++r) {
        a0m[r]     += v * f4c(w0mA, r);
        a0m[4 + r] += v * f4c(w0mB, r);
        a0l[r]     += v * f4c(w0lA, r);
        a0l[4 + r] += v * f4c(w0lB, r);
    }

    // ---- finalizers' h0 (compile-time reg Q, runtime lane t) ----
    float p0m = elu_f(rlf(a0m[Q], t)),     p0l = elu_f(rlf(a0l[Q], t));
    float p1m = elu_f(rlf(a0m[4 + Q], t)), p1l = elu_f(rlf(a0l[4 + Q], t));
    float p2m = 0.f, p2l = 0.f;
    if (EX) {
        p2m = elu_f(rlf(a0m[EX == 1 ? 3 : 7], 63));
        p2l = elu_f(rlf(a0l[EX == 1 ? 3 : 7], 63));
    }

    // ---- a1 += W1T[i]*p0 + W1T[i+255]*p1 (premasked) ----
    float4 w1amA = s4[lane],       w1amB = s4[64 + lane];
    float4 w1alA = s4[128 + lane], w1alB = s4[192 + lane];
    float4 w1bmA = s4[256 + lane], w1bmB = s4[320 + lane];
    float4 w1blA = s4[384 + lane], w1blB = s4[448 + lane];
    #pragma unroll
    for (int r = Q; r < 4; ++r) {
        a1m[r]     += f4c(w1amA, r) * p0m + f4c(w1bmA, r) * p1m;
        a1m[4 + r] += f4c(w1amB, r) * p0m + f4c(w1bmB, r) * p1m;
        a1l[r]     += f4c(w1alA, r) * p0l + f4c(w1blA, r) * p1l;
        a1l[4 + r] += f4c(w1alB, r) * p0l + f4c(w1blB, r) * p1l;
    }
    if (EX) {   // extra dh=1/2 unit's push (full range: its targets span all regs)
        #pragma unroll
        for (int r = 0; r < 4; ++r) {
            a1m[r]     += f4c(exmA, r) * p2m;
            a1m[4 + r] += f4c(exmB, r) * p2m;
            a1l[r]     += f4c(exlA, r) * p2l;
            a1l[4 + r] += f4c(exlB, r) * p2l;
        }
    }

    // ---- finalizers' h1 (their a1 is now complete) ----
    float q0m = elu_f(rlf(a1m[Q], t)),     q0l = elu_f(rlf(a1l[Q], t));
    float q1m = elu_f(rlf(a1m[4 + Q], t)), q1l = elu_f(rlf(a1l[4 + Q], t));
    float q2m = 0.f, q2l = 0.f;
    if (EX) {
        q2m = elu_f(rlf(a1m[EX == 1 ? 3 : 7], 63));
        q2l = elu_f(rlf(a1l[EX == 1 ? 3 : 7], 63));
    }

    // ---- R += WoT[i]*q0 + WoT[i+255]*q1 (dead columns harmless) ----
    float4 womA = s4[768 + lane], wolA = s4[832 + lane];
    float4 womB = s4[896 + lane], wolB = s4[960 + lane];
    #pragma unroll
    for (int r = Q; r < 4; ++r) {
        Rm[r] += f4c(womA, r) * q0m + f4c(womB, r) * q1m;
        Rl[r] += f4c(wolA, r) * q0l + f4c(wolB, r) * q1l;
    }
    if (EX) {
        #pragma unroll
        for (int r = 0; r < 4; ++r) {
            Rm[r] += f4c(exwm, r) * q2m;
            Rl[r] += f4c(exwl, r) * q2l;
        }
    }
}

__global__ __launch_bounds__(64, 1) void made_main(
    const float* __restrict__ x,
    const float* __restrict__ mu_b0, const float* __restrict__ mu_b1,
    const float* __restrict__ mu_bo,
    const float* __restrict__ lv_b0, const float* __restrict__ lv_b1,
    const float* __restrict__ lv_bo,
    const float* __restrict__ tape,
    float* __restrict__ out)
{
    __shared__ __align__(16) float ring[3 * TS];
    __shared__ __align__(16) float y_s[DD];

    const int lane = threadIdx.x;
    const int row  = blockIdx.x;

    float a0m[8], a0l[8], a1m[8], a1l[8], Rm[4], Rl[4];
    float xv[4], bmv[4], blv[4];
    #pragma unroll
    for (int r = 0; r < 4; ++r) {
        a0m[r]     = mu_b0[lane + 64 * r];
        a0m[4 + r] = mu_b0[255 + lane + 64 * r];
        a0l[r]     = lv_b0[lane + 64 * r];
        a0l[4 + r] = lv_b0[255 + lane + 64 * r];
        a1m[r]     = mu_b1[lane + 64 * r];
        a1m[4 + r] = mu_b1[255 + lane + 64 * r];
        a1l[r]     = lv_b1[lane + 64 * r];
        a1l[4 + r] = lv_b1[255 + lane + 64 * r];
        Rm[r] = 0.f; Rl[r] = 0.f;
        xv[r]  = x[row * DD + 64 * r + lane];
        bmv[r] = mu_bo[64 * r + lane];
        blv[r] = lv_bo[64 * r + lane];
    }
    if (lane == 63) {   // (63,3) slots host h=510 (A) and h=511 (B)
        a0m[3] = mu_b0[510]; a0m[7] = mu_b0[511];
        a0l[3] = lv_b0[510]; a0l[7] = lv_b0[511];
        a1m[3] = mu_b1[510]; a1m[7] = mu_b1[511];
        a1l[3] = lv_b1[510]; a1l[7] = lv_b1[511];
    }

    // appendix preloads (freed after steps 0/1)
    const float4* a4 = (const float4*)(tape + 255 * TS);
    float4 e510mA = a4[lane],       e510mB = a4[64 + lane];
    float4 e510lA = a4[128 + lane], e510lB = a4[192 + lane];
    float4 e511mA = a4[256 + lane], e511mB = a4[320 + lane];
    float4 e511lA = a4[384 + lane], e511lB = a4[448 + lane];
    float4 wo510m = a4[512 + lane], wo510l = a4[576 + lane];
    float4 wo511m = a4[640 + lane], wo511l = a4[704 + lane];

    // prefill ring: blocks 0,1
    dma16(tape + 0 * TS, ring + 0 * TS, lane);
    dma16(tape + 1 * TS, ring + 1 * TS, lane);

    float ls_sum = 0.f;
    int rd = 0;

    // ---- step 0 (extra h=510) ----
    dma16(tape + 2 * TS, ring + 2 * TS, lane);
    WAITVM(32);
    stepT<0, 1>(0, 0, lane, (const float4*)(ring), y_s,
                a0m, a0l, a1m, a1l, Rm, Rl, xv, bmv, blv, ls_sum,
                e510mA, e510mB, e510lA, e510lB, wo510m, wo510l);
    // ---- step 1 (extra h=511) ----
    dma16(tape + 3 * TS, ring + 0 * TS, lane);
    WAITVM(32);
    stepT<0, 2>(1, 1, lane, (const float4*)(ring + TS), y_s,
                a0m, a0l, a1m, a1l, Rm, Rl, xv, bmv, blv, ls_sum,
                e511mA, e511mB, e511lA, e511lB, wo511m, wo511l);
    rd = 2;

    // ---- phase 0 remainder: t=2..63 ----
    #pragma unroll 1
    for (int t = 2; t < 64; ++t) {
        int i = t;
        int wr = (rd == 0) ? 2 : rd - 1;
        int nb = i + 2 > 254 ? 254 : i + 2;
        dma16(tape + nb * TS, ring + wr * TS, lane);
        WAITVM(32);
        stepT<0, 0>(i, t, lane, (const float4*)(ring + rd * TS), y_s,
                    a0m, a0l, a1m, a1l, Rm, Rl, xv, bmv, blv, ls_sum,
                    e510mA, e510mB, e510lA, e510lB, wo510m, wo510l);
        rd = (rd == 2) ? 0 : rd + 1;
    }
    // ---- phase 1 ----
    #pragma unroll 1
    for (int t = 0; t < 64; ++t) {
        int i = 64 + t;
        int wr = (rd == 0) ? 2 : rd - 1;
        int nb = i + 2 > 254 ? 254 : i + 2;
        dma16(tape + nb * TS, ring + wr * TS, lane);
        WAITVM(32);
        stepT<1, 0>(i, t, lane, (const float4*)(ring + rd * TS), y_s,
                    a0m, a0l, a1m, a1l, Rm, Rl, xv, bmv, blv, ls_sum,
                    e510mA, e510mB, e510lA, e510lB, wo510m, wo510l);
        rd = (rd == 2) ? 0 : rd + 1;
    }
    // ---- phase 2 ----
    #pragma unroll 1
    for (int t = 0; t < 64; ++t) {
        int i = 128 + t;
        int wr = (rd == 0) ? 2 : rd - 1;
        int nb = i + 2 > 254 ? 254 : i + 2;
        dma16(tape + nb * TS, ring + wr * TS, lane);
        WAITVM(32);
        stepT<2, 0>(i, t, lane, (const float4*)(ring + rd * TS), y_s,
                    a0m, a0l, a1m, a1l, Rm, Rl, xv, bmv, blv, ls_sum,
                    e510mA, e510mB, e510lA, e510lB, wo510m, wo510l);
        rd = (rd == 2) ? 0 : rd + 1;
    }
    // ---- phase 3: t=0..62 (i=192..254) ----
    #pragma unroll 1
    for (int t = 0; t < 63; ++t) {
        int i = 192 + t;
        int wr = (rd == 0) ? 2 : rd - 1;
        int nb = i + 2 > 254 ? 254 : i + 2;
        dma16(tape + nb * TS, ring + wr * TS, lane);
        WAITVM(32);
        stepT<3, 0>(i, t, lane, (const float4*)(ring + rd * TS), y_s,
                    a0m, a0l, a1m, a1l, Rm, Rl, xv, bmv, blv, ls_sum,
                    e510mA, e510mB, e510lA, e510lB, wo510m, wo510l);
        rd = (rd == 2) ? 0 : rd + 1;
    }

    // ---- step 255: output only ----
    WAITVM(0);
    {
        float mu = rlf(Rm[3], 63) + rlf(bmv[3], 63);
        float ls = 0.5f * (rlf(Rl[3], 63) + rlf(blv[3], 63));
        ls_sum += ls;
        float v = __fdividef(rlf(xv[3], 63) - mu, __expf(ls) + 1e-12f);
        if (lane == 0) y_s[255] = v;
    }

    __syncthreads();
    ((float4*)(out + row * DD))[lane] = ((const float4*)y_s)[lane];
    if (lane == 0) out[BB * DD + row] = ls_sum;
}

extern "C" void kernel_launch(void* const* d_in, const int* in_sizes, int n_in,
                              void* d_out, int out_size, void* d_ws, size_t ws_size,
                              hipStream_t stream) {
    const float* x     = (const float*)d_in[0];
    const float* mu_W0 = (const float*)d_in[1];
    const float* mu_b0 = (const float*)d_in[2];
    const float* mu_W1 = (const float*)d_in[3];
    const float* mu_b1 = (const float*)d_in[4];
    const float* mu_Wo = (const float*)d_in[5];
    const float* mu_bo = (const float*)d_in[6];
    const float* lv_W0 = (const float*)d_in[7];
    const float* lv_b0 = (const float*)d_in[8];
    const float* lv_W1 = (const float*)d_in[9];
    const float* lv_b1 = (const float*)d_in[10];
    const float* lv_Wo = (const float*)d_in[11];
    const float* lv_bo = (const float*)d_in[12];

    float* tape = (float*)d_ws;   // 4 MiB

    prep<<<2046, 256, 0, stream>>>(mu_W0, lv_W0, mu_W1, lv_W1, mu_Wo, lv_Wo, tape);
    made_main<<<BB, 64, 0, stream>>>(x, mu_b0, mu_b1, mu_bo,
                                     lv_b0, lv_b1, lv_bo, tape, (float*)d_out);
}

// Round 8
// 248.814 us; speedup vs baseline: 1.3882x; 1.1441x over previous
//
#include <hip/hip_runtime.h>

#define DD 256
#define HH 512
#define BB 128
#define TS 4096   // floats per tape block (16 KB)

#define WAITVM(N) asm volatile("s_waitcnt vmcnt(" #N ")" ::: "memory")

__device__ __forceinline__ float elu_f(float x) {
    return x > 0.f ? x : (__expf(x) - 1.f);
}
__device__ __forceinline__ float rlf(float v, int l) {
    return __uint_as_float(__builtin_amdgcn_readlane(__float_as_uint(v), (unsigned)l));
}
__device__ __forceinline__ float f4c(const float4& v, int r) {
    return r == 0 ? v.x : r == 1 ? v.y : r == 2 ? v.z : v.w;
}
__device__ __forceinline__ void dma16(const float* __restrict__ src, float* dst, int lane) {
    const float* s = src + lane * 4;
    #pragma unroll
    for (int k = 0; k < 16; ++k) {
        __builtin_amdgcn_global_load_lds(
            (const __attribute__((address_space(1))) void*)(s + k * 256),
            (__attribute__((address_space(3))) void*)(dst + k * 256),
            16, 0, 0);
    }
}

// Unit slot map: lane L, A-reg r (0..3) <-> h = L+64r  [exception (63,3) -> h=510]
//                lane L, B-reg 4+r     <-> h = 255+L+64r [exception (63,3) -> h=511]
// Unit h finalizes at step: A: L+64r; B: L+64r; 510->step0, 511->step1.
// Column j <-> lane j&63, reg j>>6 (R accumulators and yv, 4/lane).
//
// Tape block i (4096 floats), rows packed per-lane [pos = fam*256 + 4L + r]:
//  [0]    W1T[i]     m   [512]  W1T[i]     l
//  [1024] W1T[i+255] m   [1536] W1T[i+255] l
//  [2048] W0T[i]     m   [2560] W0T[i]     l
//  [3072] WoT[i]     m   [3328] WoT[i]     l     (256 floats, pos=4L+r, j=L+64r)
//  [3584] WoT[i+255] m   [3840] WoT[i+255] l
// Block 255 = appendix: [0/512] W1T[510] m/l, [1024/1536] W1T[511] m/l,
//  [2048/2304] WoT[510] m/l, [2560/2816] WoT[511] m/l.
__global__ __launch_bounds__(256) void prep(
    const float* __restrict__ w0m_, const float* __restrict__ w0l_,
    const float* __restrict__ w1m_, const float* __restrict__ w1l_,
    const float* __restrict__ wom_, const float* __restrict__ wol_,
    float* __restrict__ tape)
{
    int t = blockIdx.x * 256 + threadIdx.x;     // < 523776
    if (t < 262144) {                           // W1T rows (hp = W1 column)
        int hp = t >> 9, p = t & 511;
        int fam = p >> 8, L = (p & 255) >> 2, r = p & 3;
        int h = (L == 63 && r == 3) ? (fam ? 511 : 510)
                                    : (fam ? 255 + L + 64 * r : L + 64 * r);
        int dh_h = (h <= 254) ? h + 1 : (h <= 509 ? h - 254 : h - 509);
        int dh_p = (hp <= 254) ? hp + 1 : (hp <= 509 ? hp - 254 : hp - 509);
        bool msk = dh_h >= dh_p;
        float vm = msk ? w1m_[h * HH + hp] : 0.f;
        float vl = msk ? w1l_[h * HH + hp] : 0.f;
        int base = (hp <= 254) ? hp * TS
                 : (hp <= 509) ? (hp - 255) * TS + 1024
                 : 255 * TS + (hp == 510 ? 0 : 1024);
        tape[base + p]       = vm;
        tape[base + 512 + p] = vl;
    } else if (t < 392704) {                    // W0T rows i=0..254
        int u = t - 262144;
        int i = u >> 9, p = u & 511;
        int fam = p >> 8, L = (p & 255) >> 2, r = p & 3;
        int h = (L == 63 && r == 3) ? (fam ? 511 : 510)
                                    : (fam ? 255 + L + 64 * r : L + 64 * r);
        tape[i * TS + 2048 + p] = w0m_[h * DD + i];
        tape[i * TS + 2560 + p] = w0l_[h * DD + i];
    } else {                                    // WoT rows (hp = Wo column)
        int u = t - 392704;
        int hp = u >> 8, p = u & 255;
        int L = p >> 2, r = p & 3;
        int j = L + 64 * r;
        int base = (hp <= 254) ? hp * TS + 3072
                 : (hp <= 509) ? (hp - 255) * TS + 3584
                 : 255 * TS + (hp == 510 ? 2048 : 2560);
        tape[base + p]       = wom_[j * HH + hp];
        tape[base + 256 + p] = wol_[j * HH + hp];
    }
}

// ================================ main =====================================
struct WSet { float4 w[16]; };

__device__ __forceinline__ void pf_set(WSet& S, const float* slot, int lane) {
    const float4* s4 = (const float4*)slot;
    #pragma unroll
    for (int k = 0; k < 16; ++k) S.w[k] = s4[64 * k + lane];
}

// w[0..3]=W1T[i] mA,mB,lA,lB  w[4..7]=W1T[i+255] mA,mB,lA,lB
// w[8..11]=W0T[i] mA,mB,lA,lB  w[12..15]=WoT[i]m, WoT[i]l, WoT[i+255]m, WoT[i+255]l
template<int Q, int EX>
__device__ __forceinline__ void stepC(
    int t, int lane, const WSet& S,
    float (&a0m)[8], float (&a0l)[8], float (&a1m)[8], float (&a1l)[8],
    float (&Rm)[4], float (&Rl)[4], float (&yv)[4],
    const float (&xv)[4], const float (&bmv)[4], const float (&blv)[4],
    float& ls_sum,
    const float4& exmA, const float4& exmB, const float4& exlA, const float4& exlB,
    const float4& exwm, const float4& exwl)
{
    float mu = rlf(Rm[Q], t) + rlf(bmv[Q], t);
    float ls = 0.5f * (rlf(Rl[Q], t) + rlf(blv[Q], t));
    ls_sum += ls;
    float v = __fdividef(rlf(xv[Q], t) - mu, __expf(ls) + 1e-12f);
    yv[Q] = (lane == t) ? v : yv[Q];

    #pragma unroll
    for (int r = Q; r < 4; ++r) {
        a0m[r]     += v * f4c(S.w[8], r);
        a0m[4 + r] += v * f4c(S.w[9], r);
        a0l[r]     += v * f4c(S.w[10], r);
        a0l[4 + r] += v * f4c(S.w[11], r);
    }

    float p0m = elu_f(rlf(a0m[Q], t)),     p0l = elu_f(rlf(a0l[Q], t));
    float p1m = elu_f(rlf(a0m[4 + Q], t)), p1l = elu_f(rlf(a0l[4 + Q], t));
    float p2m = 0.f, p2l = 0.f;
    if (EX) {
        p2m = elu_f(rlf(a0m[EX == 1 ? 3 : 7], 63));
        p2l = elu_f(rlf(a0l[EX == 1 ? 3 : 7], 63));
    }

    #pragma unroll
    for (int r = Q; r < 4; ++r) {
        a1m[r]     += f4c(S.w[0], r) * p0m + f4c(S.w[4], r) * p1m;
        a1m[4 + r] += f4c(S.w[1], r) * p0m + f4c(S.w[5], r) * p1m;
        a1l[r]     += f4c(S.w[2], r) * p0l + f4c(S.w[6], r) * p1l;
        a1l[4 + r] += f4c(S.w[3], r) * p0l + f4c(S.w[7], r) * p1l;
    }
    if (EX) {
        #pragma unroll
        for (int r = 0; r < 4; ++r) {
            a1m[r]     += f4c(exmA, r) * p2m;
            a1m[4 + r] += f4c(exmB, r) * p2m;
            a1l[r]     += f4c(exlA, r) * p2l;
            a1l[4 + r] += f4c(exlB, r) * p2l;
        }
    }

    float q0m = elu_f(rlf(a1m[Q], t)),     q0l = elu_f(rlf(a1l[Q], t));
    float q1m = elu_f(rlf(a1m[4 + Q], t)), q1l = elu_f(rlf(a1l[4 + Q], t));
    float q2m = 0.f, q2l = 0.f;
    if (EX) {
        q2m = elu_f(rlf(a1m[EX == 1 ? 3 : 7], 63));
        q2l = elu_f(rlf(a1l[EX == 1 ? 3 : 7], 63));
    }

    #pragma unroll
    for (int r = Q; r < 4; ++r) {
        Rm[r] += f4c(S.w[12], r) * q0m + f4c(S.w[14], r) * q1m;
        Rl[r] += f4c(S.w[13], r) * q0l + f4c(S.w[15], r) * q1l;
    }
    if (EX) {
        #pragma unroll
        for (int r = 0; r < 4; ++r) {
            Rm[r] += f4c(exwm, r) * q2m;
            Rl[r] += f4c(exwl, r) * q2l;
        }
    }
}

__global__ __launch_bounds__(64, 1) void made_main(
    const float* __restrict__ x,
    const float* __restrict__ mu_b0, const float* __restrict__ mu_b1,
    const float* __restrict__ mu_bo,
    const float* __restrict__ lv_b0, const float* __restrict__ lv_b1,
    const float* __restrict__ lv_bo,
    const float* __restrict__ tape,
    float* __restrict__ out)
{
    __shared__ __align__(16) float ring[4 * TS];   // 64 KB, 4-slot ring

    const int lane = threadIdx.x;
    const int row  = blockIdx.x;

    float a0m[8], a0l[8], a1m[8], a1l[8], Rm[4], Rl[4], yv[4];
    float xv[4], bmv[4], blv[4];
    #pragma unroll
    for (int r = 0; r < 4; ++r) {
        a0m[r]     = mu_b0[lane + 64 * r];
        a0m[4 + r] = mu_b0[255 + lane + 64 * r];
        a0l[r]     = lv_b0[lane + 64 * r];
        a0l[4 + r] = lv_b0[255 + lane + 64 * r];
        a1m[r]     = mu_b1[lane + 64 * r];
        a1m[4 + r] = mu_b1[255 + lane + 64 * r];
        a1l[r]     = lv_b1[lane + 64 * r];
        a1l[4 + r] = lv_b1[255 + lane + 64 * r];
        Rm[r] = 0.f; Rl[r] = 0.f; yv[r] = 0.f;
        xv[r]  = x[row * DD + 64 * r + lane];
        bmv[r] = mu_bo[64 * r + lane];
        blv[r] = lv_bo[64 * r + lane];
    }
    if (lane == 63) {   // (63,3) slots host h=510 (A) and h=511 (B)
        a0m[3] = mu_b0[510]; a0m[7] = mu_b0[511];
        a0l[3] = lv_b0[510]; a0l[7] = lv_b0[511];
        a1m[3] = mu_b1[510]; a1m[7] = mu_b1[511];
        a1l[3] = lv_b1[510]; a1l[7] = lv_b1[511];
    }

    // appendix preloads (dead after steps 0/1; registers recycled)
    const float4* a4 = (const float4*)(tape + 255 * TS);
    float4 e510mA = a4[lane],       e510mB = a4[64 + lane];
    float4 e510lA = a4[128 + lane], e510lB = a4[192 + lane];
    float4 e511mA = a4[256 + lane], e511mB = a4[320 + lane];
    float4 e511lA = a4[384 + lane], e511lB = a4[448 + lane];
    float4 wo510m = a4[512 + lane], wo510l = a4[576 + lane];
    float4 wo511m = a4[640 + lane], wo511l = a4[704 + lane];

    const float4 d4 = make_float4(0.f, 0.f, 0.f, 0.f);

    // prefill: groups 0,1,2
    dma16(tape + 0 * TS, ring + 0 * TS, lane);
    dma16(tape + 1 * TS, ring + 1 * TS, lane);
    dma16(tape + 2 * TS, ring + 2 * TS, lane);

    WSet P, N;
    WAITVM(32);                 // appendix + group 0 landed
    pf_set(P, ring + 0 * TS, lane);

    float ls_sum = 0.f;

    // ---- step 0 (extra h=510) ----
    dma16(tape + 3 * TS, ring + 3 * TS, lane);
    WAITVM(32);                 // group 1 landed
    pf_set(N, ring + 1 * TS, lane);
    stepC<0, 1>(0, lane, P, a0m, a0l, a1m, a1l, Rm, Rl, yv, xv, bmv, blv, ls_sum,
                e510mA, e510mB, e510lA, e510lB, wo510m, wo510l);

    // ---- step 1 (extra h=511) ----
    dma16(tape + 4 * TS, ring + 0 * TS, lane);
    WAITVM(32);                 // group 2 landed
    pf_set(P, ring + 2 * TS, lane);
    stepC<0, 2>(1, lane, N, a0m, a0l, a1m, a1l, Rm, Rl, yv, xv, bmv, blv, ls_sum,
                e511mA, e511mB, e511lA, e511lB, wo511m, wo511l);

#define PAIR_BODY(Q, i, t)                                                    \
    {                                                                         \
        int g3 = (i) + 3 > 254 ? 254 : (i) + 3;                               \
        int g4 = (i) + 4 > 254 ? 254 : (i) + 4;                               \
        dma16(tape + (size_t)g3 * TS, ring + (((i) + 3) & 3) * TS, lane);     \
        WAITVM(32);                                                           \
        pf_set(N, ring + (((i) + 1) & 3) * TS, lane);                         \
        stepC<Q, 0>((t), lane, P, a0m, a0l, a1m, a1l, Rm, Rl, yv,             \
                    xv, bmv, blv, ls_sum, d4, d4, d4, d4, d4, d4);            \
        dma16(tape + (size_t)g4 * TS, ring + (((i) + 4) & 3) * TS, lane);     \
        WAITVM(32);                                                           \
        pf_set(P, ring + (((i) + 2) & 3) * TS, lane);                         \
        stepC<Q, 0>((t) + 1, lane, N, a0m, a0l, a1m, a1l, Rm, Rl, yv,         \
                    xv, bmv, blv, ls_sum, d4, d4, d4, d4, d4, d4);            \
    }

    #pragma unroll 1
    for (int i = 2; i < 64; i += 2)   PAIR_BODY(0, i, i)
    #pragma unroll 1
    for (int i = 64; i < 128; i += 2) PAIR_BODY(1, i, i - 64)
    #pragma unroll 1
    for (int i = 128; i < 192; i += 2) PAIR_BODY(2, i, i - 128)
    #pragma unroll 1
    for (int i = 192; i < 254; i += 2) PAIR_BODY(3, i, i - 192)
#undef PAIR_BODY

    // ---- step 254: P holds group 254 (prefetched during step 253) ----
    stepC<3, 0>(62, lane, P, a0m, a0l, a1m, a1l, Rm, Rl, yv, xv, bmv, blv, ls_sum,
                d4, d4, d4, d4, d4, d4);

    // ---- step 255: output only ----
    {
        float mu = rlf(Rm[3], 63) + rlf(bmv[3], 63);
        float ls = 0.5f * (rlf(Rl[3], 63) + rlf(blv[3], 63));
        ls_sum += ls;
        float v = __fdividef(rlf(xv[3], 63) - mu, __expf(ls) + 1e-12f);
        yv[3] = (lane == 63) ? v : yv[3];
    }

    #pragma unroll
    for (int r = 0; r < 4; ++r) out[row * DD + 64 * r + lane] = yv[r];
    if (lane == 0) out[BB * DD + row] = ls_sum;
}

extern "C" void kernel_launch(void* const* d_in, const int* in_sizes, int n_in,
                              void* d_out, int out_size, void* d_ws, size_t ws_size,
                              hipStream_t stream) {
    const float* x     = (const float*)d_in[0];
    const float* mu_W0 = (const float*)d_in[1];
    const float* mu_b0 = (const float*)d_in[2];
    const float* mu_W1 = (const float*)d_in[3];
    const float* mu_b1 = (const float*)d_in[4];
    const float* mu_Wo = (const float*)d_in[5];
    const float* mu_bo = (const float*)d_in[6];
    const float* lv_W0 = (const float*)d_in[7];
    const float* lv_b0 = (const float*)d_in[8];
    const float* lv_W1 = (const float*)d_in[9];
    const float* lv_b1 = (const float*)d_in[10];
    const float* lv_Wo = (const float*)d_in[11];
    const float* lv_bo = (const float*)d_in[12];

    float* tape = (float*)d_ws;   // 4 MiB

    prep<<<2046, 256, 0, stream>>>(mu_W0, lv_W0, mu_W1, lv_W1, mu_Wo, lv_Wo, tape);
    made_main<<<BB, 64, 0, stream>>>(x, mu_b0, mu_b1, mu_bo,
                                     lv_b0, lv_b1, lv_bo, tape, (float*)d_out);
}

// Round 9
// 208.557 us; speedup vs baseline: 1.6562x; 1.1930x over previous
//
#include <hip/hip_runtime.h>

#define DD 256
#define HH 512
#define BB 128
#define TS 4096   // floats per tape block (16 KB)

#define WAITVM(N) asm volatile("s_waitcnt vmcnt(" #N ")" ::: "memory")

__device__ __forceinline__ float elu_f(float x) {
    return x > 0.f ? x : (__expf(x) - 1.f);
}
__device__ __forceinline__ float rlf(float v, int l) {
    return __uint_as_float(__builtin_amdgcn_readlane(__float_as_uint(v), (unsigned)l));
}
__device__ __forceinline__ float f4c(const float4& v, int r) {
    return r == 0 ? v.x : r == 1 ? v.y : r == 2 ? v.z : v.w;
}

// Unit slot map: lane L, A-reg r (0..3) <-> h = L+64r  [exception (63,3) -> h=510]
//                lane L, B-reg 4+r     <-> h = 255+L+64r [exception (63,3) -> h=511]
// lane-packed position p(h) within a 512-float tape row:
__device__ __forceinline__ int pmap(int h) {
    if (h == 510) return 255;
    if (h == 511) return 511;
    return (h < 255) ? (4 * (h & 63) + (h >> 6))
                     : (256 + 4 * ((h - 255) & 63) + ((h - 255) >> 6));
}
__device__ __forceinline__ int p4map(int j) {      // j in [0,256): column map
    return 4 * (j & 63) + (j >> 6);
}
__device__ __forceinline__ int w1base(int hp) {    // m at +0, l at +512
    return (hp <= 254) ? hp * TS
         : (hp <= 509) ? (hp - 255) * TS + 1024
         : 255 * TS + ((hp == 510) ? 0 : 1024);
}
__device__ __forceinline__ int wobase(int hp) {    // m at +0, l at +256
    return (hp <= 254) ? hp * TS + 3072
         : (hp <= 509) ? (hp - 255) * TS + 3584
         : 255 * TS + ((hp == 510) ? 2048 : 2560);
}

// Tape block i (4096 floats), rows lane-packed [pos = p(h) or p4(j)]:
//  [0/512]    W1T[i]     m/l     [1024/1536] W1T[i+255] m/l
//  [2048/2560] W0T[i]    m/l     [3072/3328] WoT[i]     m/l (256)
//  [3584/3840] WoT[i+255] m/l
// Block 255 = appendix: W1T[510] m/l @0/512, W1T[511] m/l @1024/1536,
//  WoT[510] m/l @2048/2304, WoT[511] m/l @2560/2816.
// Fully-coalesced reads via 32x33 LDS tiles; permuted writes (stride-4, L2-absorbed).
__global__ __launch_bounds__(256) void prep(
    const float* __restrict__ w0m_, const float* __restrict__ w0l_,
    const float* __restrict__ w1m_, const float* __restrict__ w1l_,
    const float* __restrict__ wom_, const float* __restrict__ wol_,
    float* __restrict__ tape)
{
    __shared__ float tm[32][33], tl[32][33];
    const int tx = threadIdx.x & 31, ty = threadIdx.x >> 5;
    const unsigned b = blockIdx.x;

    if (b < 256) {                              // W1: 16 h-tiles x 16 hp-tiles
        const int h0 = (int)(b >> 4) << 5, hp0 = (int)(b & 15) << 5;
        #pragma unroll
        for (int j = 0; j < 4; ++j) {
            int r = ty + 8 * j;
            tm[r][tx] = w1m_[(h0 + r) * HH + hp0 + tx];
            tl[r][tx] = w1l_[(h0 + r) * HH + hp0 + tx];
        }
        __syncthreads();
        #pragma unroll
        for (int j = 0; j < 4; ++j) {
            int hp = hp0 + ty + 8 * j;
            int h  = h0 + tx;
            int dh_h = (h <= 254) ? h + 1 : (h <= 509 ? h - 254 : h - 509);
            int dh_p = (hp <= 254) ? hp + 1 : (hp <= 509 ? hp - 254 : hp - 509);
            float mask = (dh_h >= dh_p) ? 1.f : 0.f;
            int base = w1base(hp), p = pmap(h);
            tape[base + p]       = mask * tm[tx][ty + 8 * j];
            tape[base + 512 + p] = mask * tl[tx][ty + 8 * j];
        }
    } else if (b < 384) {                       // W0: 16 h-tiles x 8 i-tiles
        const int b2 = (int)b - 256;
        const int h0 = (b2 >> 3) << 5, i0 = (b2 & 7) << 5;
        #pragma unroll
        for (int j = 0; j < 4; ++j) {
            int r = ty + 8 * j;
            tm[r][tx] = w0m_[(h0 + r) * DD + i0 + tx];
            tl[r][tx] = w0l_[(h0 + r) * DD + i0 + tx];
        }
        __syncthreads();
        #pragma unroll
        for (int j = 0; j < 4; ++j) {
            int i = i0 + ty + 8 * j;
            int h = h0 + tx;
            int p = pmap(h);
            tape[i * TS + 2048 + p] = tm[tx][ty + 8 * j];
            tape[i * TS + 2560 + p] = tl[tx][ty + 8 * j];
        }
    } else {                                    // Wo: 8 j-tiles x 16 hp-tiles
        const int b3 = (int)b - 384;
        const int j0 = (b3 >> 4) << 5, hp0 = (b3 & 15) << 5;
        #pragma unroll
        for (int j = 0; j < 4; ++j) {
            int r = ty + 8 * j;
            tm[r][tx] = wom_[(j0 + r) * HH + hp0 + tx];
            tl[r][tx] = wol_[(j0 + r) * HH + hp0 + tx];
        }
        __syncthreads();
        #pragma unroll
        for (int j = 0; j < 4; ++j) {
            int hp = hp0 + ty + 8 * j;
            int jj = j0 + tx;
            int base = wobase(hp), p = p4map(jj);
            tape[base + p]       = tm[tx][ty + 8 * j];
            tape[base + 256 + p] = tl[tx][ty + 8 * j];
        }
    }
}

// ================================ main =====================================
struct WSet { float4 w[16]; };

__device__ __forceinline__ void ld_set(WSet& S, const float* __restrict__ g, int lane) {
    const float4* p = (const float4*)g;
    #pragma unroll
    for (int k = 0; k < 16; ++k) S.w[k] = p[64 * k + lane];
}

// w[0..3]=W1T[i] mA,mB,lA,lB  w[4..7]=W1T[i+255] mA,mB,lA,lB
// w[8..11]=W0T[i] mA,mB,lA,lB  w[12..15]=WoT[i]m, WoT[i]l, WoT[i+255]m, WoT[i+255]l
template<int Q, int EX>
__device__ __forceinline__ void stepC(
    int t, int lane, const WSet& S,
    float (&a0m)[8], float (&a0l)[8], float (&a1m)[8], float (&a1l)[8],
    float (&Rm)[4], float (&Rl)[4], float (&yv)[4],
    const float (&xv)[4], const float (&bmv)[4], const float (&blv)[4],
    float& ls_sum,
    const float4& exmA, const float4& exmB, const float4& exlA, const float4& exlB,
    const float4& exwm, const float4& exwl)
{
    float mu = rlf(Rm[Q], t) + rlf(bmv[Q], t);
    float ls = 0.5f * (rlf(Rl[Q], t) + rlf(blv[Q], t));
    ls_sum += ls;
    float v = __fdividef(rlf(xv[Q], t) - mu, __expf(ls) + 1e-12f);
    yv[Q] = (lane == t) ? v : yv[Q];

    #pragma unroll
    for (int r = Q; r < 4; ++r) {
        a0m[r]     += v * f4c(S.w[8], r);
        a0m[4 + r] += v * f4c(S.w[9], r);
        a0l[r]     += v * f4c(S.w[10], r);
        a0l[4 + r] += v * f4c(S.w[11], r);
    }

    float p0m = elu_f(rlf(a0m[Q], t)),     p0l = elu_f(rlf(a0l[Q], t));
    float p1m = elu_f(rlf(a0m[4 + Q], t)), p1l = elu_f(rlf(a0l[4 + Q], t));
    float p2m = 0.f, p2l = 0.f;
    if (EX) {
        p2m = elu_f(rlf(a0m[EX == 1 ? 3 : 7], 63));
        p2l = elu_f(rlf(a0l[EX == 1 ? 3 : 7], 63));
    }

    #pragma unroll
    for (int r = Q; r < 4; ++r) {
        a1m[r]     += f4c(S.w[0], r) * p0m + f4c(S.w[4], r) * p1m;
        a1m[4 + r] += f4c(S.w[1], r) * p0m + f4c(S.w[5], r) * p1m;
        a1l[r]     += f4c(S.w[2], r) * p0l + f4c(S.w[6], r) * p1l;
        a1l[4 + r] += f4c(S.w[3], r) * p0l + f4c(S.w[7], r) * p1l;
    }
    if (EX) {
        #pragma unroll
        for (int r = 0; r < 4; ++r) {
            a1m[r]     += f4c(exmA, r) * p2m;
            a1m[4 + r] += f4c(exmB, r) * p2m;
            a1l[r]     += f4c(exlA, r) * p2l;
            a1l[4 + r] += f4c(exlB, r) * p2l;
        }
    }

    float q0m = elu_f(rlf(a1m[Q], t)),     q0l = elu_f(rlf(a1l[Q], t));
    float q1m = elu_f(rlf(a1m[4 + Q], t)), q1l = elu_f(rlf(a1l[4 + Q], t));
    float q2m = 0.f, q2l = 0.f;
    if (EX) {
        q2m = elu_f(rlf(a1m[EX == 1 ? 3 : 7], 63));
        q2l = elu_f(rlf(a1l[EX == 1 ? 3 : 7], 63));
    }

    #pragma unroll
    for (int r = Q; r < 4; ++r) {
        Rm[r] += f4c(S.w[12], r) * q0m + f4c(S.w[14], r) * q1m;
        Rl[r] += f4c(S.w[13], r) * q0l + f4c(S.w[15], r) * q1l;
    }
    if (EX) {
        #pragma unroll
        for (int r = 0; r < 4; ++r) {
            Rm[r] += f4c(exwm, r) * q2m;
            Rl[r] += f4c(exwl, r) * q2l;
        }
    }
}

__global__ __launch_bounds__(64, 1) void made_main(
    const float* __restrict__ x,
    const float* __restrict__ mu_b0, const float* __restrict__ mu_b1,
    const float* __restrict__ mu_bo,
    const float* __restrict__ lv_b0, const float* __restrict__ lv_b1,
    const float* __restrict__ lv_bo,
    const float* __restrict__ tape,
    float* __restrict__ out)
{
    const int lane = threadIdx.x;
    const int row  = blockIdx.x;

    float a0m[8], a0l[8], a1m[8], a1l[8], Rm[4], Rl[4], yv[4];
    float xv[4], bmv[4], blv[4];
    #pragma unroll
    for (int r = 0; r < 4; ++r) {
        a0m[r]     = mu_b0[lane + 64 * r];
        a0m[4 + r] = mu_b0[255 + lane + 64 * r];
        a0l[r]     = lv_b0[lane + 64 * r];
        a0l[4 + r] = lv_b0[255 + lane + 64 * r];
        a1m[r]     = mu_b1[lane + 64 * r];
        a1m[4 + r] = mu_b1[255 + lane + 64 * r];
        a1l[r]     = lv_b1[lane + 64 * r];
        a1l[4 + r] = lv_b1[255 + lane + 64 * r];
        Rm[r] = 0.f; Rl[r] = 0.f; yv[r] = 0.f;
        xv[r]  = x[row * DD + 64 * r + lane];
        bmv[r] = mu_bo[64 * r + lane];
        blv[r] = lv_bo[64 * r + lane];
    }
    if (lane == 63) {   // (63,3) slots host h=510 (A) and h=511 (B)
        a0m[3] = mu_b0[510]; a0m[7] = mu_b0[511];
        a0l[3] = lv_b0[510]; a0l[7] = lv_b0[511];
        a1m[3] = mu_b1[510]; a1m[7] = mu_b1[511];
        a1l[3] = lv_b1[510]; a1l[7] = lv_b1[511];
    }

    // appendix preloads (dead after steps 0/1)
    const float4* a4 = (const float4*)(tape + 255 * TS);
    float4 e510mA = a4[lane],       e510mB = a4[64 + lane];
    float4 e510lA = a4[128 + lane], e510lB = a4[192 + lane];
    float4 e511mA = a4[256 + lane], e511mB = a4[320 + lane];
    float4 e511lA = a4[384 + lane], e511lB = a4[448 + lane];
    float4 wo510m = a4[512 + lane], wo510l = a4[576 + lane];
    float4 wo511m = a4[640 + lane], wo511l = a4[704 + lane];

    const float4 d4 = make_float4(0.f, 0.f, 0.f, 0.f);

    WSet A, B;
    ld_set(A, tape + 0 * TS, lane);     // group 0
    ld_set(B, tape + 1 * TS, lane);     // group 1

    float ls_sum = 0.f;

    // ---- step 0 (extra h=510) ----
    WAITVM(16);                          // A resident; B may fly
    stepC<0, 1>(0, lane, A, a0m, a0l, a1m, a1l, Rm, Rl, yv, xv, bmv, blv, ls_sum,
                e510mA, e510mB, e510lA, e510lB, wo510m, wo510l);
    ld_set(A, tape + 2 * TS, lane);

    // ---- step 1 (extra h=511) ----
    WAITVM(16);
    stepC<0, 2>(1, lane, B, a0m, a0l, a1m, a1l, Rm, Rl, yv, xv, bmv, blv, ls_sum,
                e511mA, e511mB, e511lA, e511lB, wo511m, wo511l);
    ld_set(B, tape + 3 * TS, lane);

#define PAIR_BODY(Q, i, t)                                                    \
    {                                                                         \
        int gA = (i) + 2 > 254 ? 254 : (i) + 2;                               \
        int gB = (i) + 3 > 254 ? 254 : (i) + 3;                               \
        WAITVM(16);                                                           \
        stepC<Q, 0>((t), lane, A, a0m, a0l, a1m, a1l, Rm, Rl, yv,             \
                    xv, bmv, blv, ls_sum, d4, d4, d4, d4, d4, d4);            \
        ld_set(A, tape + (size_t)gA * TS, lane);                              \
        WAITVM(16);                                                           \
        stepC<Q, 0>((t) + 1, lane, B, a0m, a0l, a1m, a1l, Rm, Rl, yv,         \
                    xv, bmv, blv, ls_sum, d4, d4, d4, d4, d4, d4);            \
        ld_set(B, tape + (size_t)gB * TS, lane);                              \
    }

    #pragma unroll 1
    for (int i = 2; i < 64; i += 2)    PAIR_BODY(0, i, i)
    #pragma unroll 1
    for (int i = 64; i < 128; i += 2)  PAIR_BODY(1, i, i - 64)
    #pragma unroll 1
    for (int i = 128; i < 192; i += 2) PAIR_BODY(2, i, i - 128)
    #pragma unroll 1
    for (int i = 192; i < 254; i += 2) PAIR_BODY(3, i, i - 192)
#undef PAIR_BODY

    // ---- step 254 (A = group 254; compiler's exact vmcnt covers residency) ----
    WAITVM(16);
    stepC<3, 0>(62, lane, A, a0m, a0l, a1m, a1l, Rm, Rl, yv, xv, bmv, blv, ls_sum,
                d4, d4, d4, d4, d4, d4);

    // ---- step 255: output only ----
    {
        float mu = rlf(Rm[3], 63) + rlf(bmv[3], 63);
        float ls = 0.5f * (rlf(Rl[3], 63) + rlf(blv[3], 63));
        ls_sum += ls;
        float v = __fdividef(rlf(xv[3], 63) - mu, __expf(ls) + 1e-12f);
        yv[3] = (lane == 63) ? v : yv[3];
    }

    #pragma unroll
    for (int r = 0; r < 4; ++r) out[row * DD + 64 * r + lane] = yv[r];
    if (lane == 0) out[BB * DD + row] = ls_sum;
}

extern "C" void kernel_launch(void* const* d_in, const int* in_sizes, int n_in,
                              void* d_out, int out_size, void* d_ws, size_t ws_size,
                              hipStream_t stream) {
    const float* x     = (const float*)d_in[0];
    const float* mu_W0 = (const float*)d_in[1];
    const float* mu_b0 = (const float*)d_in[2];
    const float* mu_W1 = (const float*)d_in[3];
    const float* mu_b1 = (const float*)d_in[4];
    const float* mu_Wo = (const float*)d_in[5];
    const float* mu_bo = (const float*)d_in[6];
    const float* lv_W0 = (const float*)d_in[7];
    const float* lv_b0 = (const float*)d_in[8];
    const float* lv_W1 = (const float*)d_in[9];
    const float* lv_b1 = (const float*)d_in[10];
    const float* lv_Wo = (const float*)d_in[11];
    const float* lv_bo = (const float*)d_in[12];

    float* tape = (float*)d_ws;   // 4 MiB

    prep<<<512, 256, 0, stream>>>(mu_W0, lv_W0, mu_W1, lv_W1, mu_Wo, lv_Wo, tape);
    made_main<<<BB, 64, 0, stream>>>(x, mu_b0, mu_b1, mu_bo,
                                     lv_b0, lv_b1, lv_bo, tape, (float*)d_out);
}

// Round 10
// 200.645 us; speedup vs baseline: 1.7215x; 1.0394x over previous
//
#include <hip/hip_runtime.h>

#define DD 256
#define HH 512
#define BB 128
#define TS 4096   // floats per tape block (16 KB)

#define WAITVM(N) asm volatile("s_waitcnt vmcnt(" #N ")" ::: "memory")

__device__ __forceinline__ float elu_f(float x) {
    return x > 0.f ? x : (__expf(x) - 1.f);
}
__device__ __forceinline__ float rlf(float v, int l) {
    return __uint_as_float(__builtin_amdgcn_readlane(__float_as_uint(v), (unsigned)l));
}
__device__ __forceinline__ float f4c(const float4& v, int r) {
    return r == 0 ? v.x : r == 1 ? v.y : r == 2 ? v.z : v.w;
}

// Unit slot map: lane L, A-reg r (0..3) <-> h = L+64r  [exception (63,3) -> h=510]
//                lane L, B-reg 4+r     <-> h = 255+L+64r [exception (63,3) -> h=511]
__device__ __forceinline__ int pmap(int h) {
    if (h == 510) return 255;
    if (h == 511) return 511;
    return (h < 255) ? (4 * (h & 63) + (h >> 6))
                     : (256 + 4 * ((h - 255) & 63) + ((h - 255) >> 6));
}
__device__ __forceinline__ int p4map(int j) {      // j in [0,256): column map
    return 4 * (j & 63) + (j >> 6);
}
__device__ __forceinline__ int w1base(int hp) {    // m at +0, l at +512
    return (hp <= 254) ? hp * TS
         : (hp <= 509) ? (hp - 255) * TS + 1024
         : 255 * TS + ((hp == 510) ? 0 : 1024);
}
__device__ __forceinline__ int wobase(int hp) {    // m at +0, l at +256
    return (hp <= 254) ? hp * TS + 3072
         : (hp <= 509) ? (hp - 255) * TS + 3584
         : 255 * TS + ((hp == 510) ? 2048 : 2560);
}

// Tape block i (4096 floats), rows lane-packed [pos = p(h) or p4(j)]:
//  [0/512]    W1T[i]     m/l     [1024/1536] W1T[i+255] m/l
//  [2048/2560] W0T[i]    m/l     [3072/3328] WoT[i]     m/l (256)
//  [3584/3840] WoT[i+255] m/l
// Block 255 = appendix: W1T[510] m/l @0/512, W1T[511] m/l @1024/1536,
//  WoT[510] m/l @2048/2304, WoT[511] m/l @2560/2816.  [3072..4095 unused]
__global__ __launch_bounds__(256) void prep(
    const float* __restrict__ w0m_, const float* __restrict__ w0l_,
    const float* __restrict__ w1m_, const float* __restrict__ w1l_,
    const float* __restrict__ wom_, const float* __restrict__ wol_,
    float* __restrict__ tape)
{
    __shared__ float tm[32][33], tl[32][33];
    const int tx = threadIdx.x & 31, ty = threadIdx.x >> 5;
    const unsigned b = blockIdx.x;

    if (b < 256) {                              // W1: 16 h-tiles x 16 hp-tiles
        const int h0 = (int)(b >> 4) << 5, hp0 = (int)(b & 15) << 5;
        #pragma unroll
        for (int j = 0; j < 4; ++j) {
            int r = ty + 8 * j;
            tm[r][tx] = w1m_[(h0 + r) * HH + hp0 + tx];
            tl[r][tx] = w1l_[(h0 + r) * HH + hp0 + tx];
        }
        __syncthreads();
        #pragma unroll
        for (int j = 0; j < 4; ++j) {
            int hp = hp0 + ty + 8 * j;
            int h  = h0 + tx;
            int dh_h = (h <= 254) ? h + 1 : (h <= 509 ? h - 254 : h - 509);
            int dh_p = (hp <= 254) ? hp + 1 : (hp <= 509 ? hp - 254 : hp - 509);
            float mask = (dh_h >= dh_p) ? 1.f : 0.f;
            int base = w1base(hp), p = pmap(h);
            tape[base + p]       = mask * tm[tx][ty + 8 * j];
            tape[base + 512 + p] = mask * tl[tx][ty + 8 * j];
        }
    } else if (b < 384) {                       // W0: 16 h-tiles x 8 i-tiles
        const int b2 = (int)b - 256;
        const int h0 = (b2 >> 3) << 5, i0 = (b2 & 7) << 5;
        #pragma unroll
        for (int j = 0; j < 4; ++j) {
            int r = ty + 8 * j;
            tm[r][tx] = w0m_[(h0 + r) * DD + i0 + tx];
            tl[r][tx] = w0l_[(h0 + r) * DD + i0 + tx];
        }
        __syncthreads();
        #pragma unroll
        for (int j = 0; j < 4; ++j) {
            int i = i0 + ty + 8 * j;
            int h = h0 + tx;
            int p = pmap(h);
            tape[i * TS + 2048 + p] = tm[tx][ty + 8 * j];
            tape[i * TS + 2560 + p] = tl[tx][ty + 8 * j];
        }
    } else {                                    // Wo: 8 j-tiles x 16 hp-tiles
        const int b3 = (int)b - 384;
        const int j0 = (b3 >> 4) << 5, hp0 = (b3 & 15) << 5;
        #pragma unroll
        for (int j = 0; j < 4; ++j) {
            int r = ty + 8 * j;
            tm[r][tx] = wom_[(j0 + r) * HH + hp0 + tx];
            tl[r][tx] = wol_[(j0 + r) * HH + hp0 + tx];
        }
        __syncthreads();
        #pragma unroll
        for (int j = 0; j < 4; ++j) {
            int hp = hp0 + ty + 8 * j;
            int jj = j0 + tx;
            int base = wobase(hp), p = p4map(jj);
            tape[base + p]       = tm[tx][ty + 8 * j];
            tape[base + 256 + p] = tl[tx][ty + 8 * j];
        }
    }
}

// ================================ main =====================================
struct WSet { float4 w[16]; };

__device__ __forceinline__ void ld_set(WSet& S, const float* __restrict__ g, int lane) {
    const float4* p = (const float4*)g;
    #pragma unroll
    for (int k = 0; k < 16; ++k) S.w[k] = p[64 * k + lane];
}

// w[0..3]=W1T[i] mA,mB,lA,lB  w[4..7]=W1T[i+255] mA,mB,lA,lB
// w[8..11]=W0T[i] mA,mB,lA,lB  w[12..15]=WoT[i]m, WoT[i]l, WoT[i+255]m, WoT[i+255]l
template<int Q, int EX>
__device__ __forceinline__ void stepC(
    int t, int lane, const WSet& S,
    float (&a0m)[8], float (&a0l)[8], float (&a1m)[8], float (&a1l)[8],
    float (&Rm)[4], float (&Rl)[4], float (&yv)[4],
    const float (&xv)[4], const float (&bmv)[4], const float (&blv)[4],
    float& ls_sum,
    const float4& exmA, const float4& exmB, const float4& exlA, const float4& exlB,
    const float4& exwm, const float4& exwl)
{
    float mu = rlf(Rm[Q], t) + rlf(bmv[Q], t);
    float ls = 0.5f * (rlf(Rl[Q], t) + rlf(blv[Q], t));
    ls_sum += ls;
    float v = __fdividef(rlf(xv[Q], t) - mu, __expf(ls) + 1e-12f);
    yv[Q] = (lane == t) ? v : yv[Q];

    #pragma unroll
    for (int r = Q; r < 4; ++r) {
        a0m[r]     += v * f4c(S.w[8], r);
        a0m[4 + r] += v * f4c(S.w[9], r);
        a0l[r]     += v * f4c(S.w[10], r);
        a0l[4 + r] += v * f4c(S.w[11], r);
    }

    float p0m = elu_f(rlf(a0m[Q], t)),     p0l = elu_f(rlf(a0l[Q], t));
    float p1m = elu_f(rlf(a0m[4 + Q], t)), p1l = elu_f(rlf(a0l[4 + Q], t));
    float p2m = 0.f, p2l = 0.f;
    if (EX) {
        p2m = elu_f(rlf(a0m[EX == 1 ? 3 : 7], 63));
        p2l = elu_f(rlf(a0l[EX == 1 ? 3 : 7], 63));
    }

    #pragma unroll
    for (int r = Q; r < 4; ++r) {
        a1m[r]     += f4c(S.w[0], r) * p0m + f4c(S.w[4], r) * p1m;
        a1m[4 + r] += f4c(S.w[1], r) * p0m + f4c(S.w[5], r) * p1m;
        a1l[r]     += f4c(S.w[2], r) * p0l + f4c(S.w[6], r) * p1l;
        a1l[4 + r] += f4c(S.w[3], r) * p0l + f4c(S.w[7], r) * p1l;
    }
    if (EX) {
        #pragma unroll
        for (int r = 0; r < 4; ++r) {
            a1m[r]     += f4c(exmA, r) * p2m;
            a1m[4 + r] += f4c(exmB, r) * p2m;
            a1l[r]     += f4c(exlA, r) * p2l;
            a1l[4 + r] += f4c(exlB, r) * p2l;
        }
    }

    float q0m = elu_f(rlf(a1m[Q], t)),     q0l = elu_f(rlf(a1l[Q], t));
    float q1m = elu_f(rlf(a1m[4 + Q], t)), q1l = elu_f(rlf(a1l[4 + Q], t));
    float q2m = 0.f, q2l = 0.f;
    if (EX) {
        q2m = elu_f(rlf(a1m[EX == 1 ? 3 : 7], 63));
        q2l = elu_f(rlf(a1l[EX == 1 ? 3 : 7], 63));
    }

    #pragma unroll
    for (int r = Q; r < 4; ++r) {
        Rm[r] += f4c(S.w[12], r) * q0m + f4c(S.w[14], r) * q1m;
        Rl[r] += f4c(S.w[13], r) * q0l + f4c(S.w[15], r) * q1l;
    }
    if (EX) {
        #pragma unroll
        for (int r = 0; r < 4; ++r) {
            Rm[r] += f4c(exwm, r) * q2m;
            Rl[r] += f4c(exwl, r) * q2l;
        }
    }
}

__global__ __launch_bounds__(128, 1) void made_main(
    const float* __restrict__ x,
    const float* __restrict__ mu_b0, const float* __restrict__ mu_b1,
    const float* __restrict__ mu_bo,
    const float* __restrict__ lv_b0, const float* __restrict__ lv_b1,
    const float* __restrict__ lv_bo,
    const float* __restrict__ tape,
    float* __restrict__ out)
{
    const int row = blockIdx.x;

    // ===== wave 1: L2 prefetcher — stream the full tape, staggered start =====
    if (threadIdx.x >= 64) {
        const int lane = threadIdx.x - 64;
        const int sg = ((row >> 3) & 15) << 4;     // start group, 16 offsets
        unsigned acc = 0;
        #pragma unroll 1
        for (int k = 0; k < 256; ++k) {
            int g = (sg + k) & 255;
            const uint4* p = (const uint4*)(tape + (size_t)g * TS);
            uint4 v[16];
            #pragma unroll
            for (int j = 0; j < 16; ++j) v[j] = p[64 * j + lane];
            #pragma unroll
            for (int j = 0; j < 16; ++j) acc ^= v[j].x ^ v[j].y ^ v[j].z ^ v[j].w;
        }
        // unprovable-dead sink (target is the unused appendix tail — harmless if hit)
        if (acc == 0xDEADBEEFu) ((unsigned*)tape)[255 * TS + 4000] = acc;
        return;
    }

    // ===== wave 0: main serial loop (identical to round 9) =====
    const int lane = threadIdx.x;

    float a0m[8], a0l[8], a1m[8], a1l[8], Rm[4], Rl[4], yv[4];
    float xv[4], bmv[4], blv[4];
    #pragma unroll
    for (int r = 0; r < 4; ++r) {
        a0m[r]     = mu_b0[lane + 64 * r];
        a0m[4 + r] = mu_b0[255 + lane + 64 * r];
        a0l[r]     = lv_b0[lane + 64 * r];
        a0l[4 + r] = lv_b0[255 + lane + 64 * r];
        a1m[r]     = mu_b1[lane + 64 * r];
        a1m[4 + r] = mu_b1[255 + lane + 64 * r];
        a1l[r]     = lv_b1[lane + 64 * r];
        a1l[4 + r] = lv_b1[255 + lane + 64 * r];
        Rm[r] = 0.f; Rl[r] = 0.f; yv[r] = 0.f;
        xv[r]  = x[row * DD + 64 * r + lane];
        bmv[r] = mu_bo[64 * r + lane];
        blv[r] = lv_bo[64 * r + lane];
    }
    if (lane == 63) {   // (63,3) slots host h=510 (A) and h=511 (B)
        a0m[3] = mu_b0[510]; a0m[7] = mu_b0[511];
        a0l[3] = lv_b0[510]; a0l[7] = lv_b0[511];
        a1m[3] = mu_b1[510]; a1m[7] = mu_b1[511];
        a1l[3] = lv_b1[510]; a1l[7] = lv_b1[511];
    }

    // appendix preloads (dead after steps 0/1)
    const float4* a4 = (const float4*)(tape + 255 * TS);
    float4 e510mA = a4[lane],       e510mB = a4[64 + lane];
    float4 e510lA = a4[128 + lane], e510lB = a4[192 + lane];
    float4 e511mA = a4[256 + lane], e511mB = a4[320 + lane];
    float4 e511lA = a4[384 + lane], e511lB = a4[448 + lane];
    float4 wo510m = a4[512 + lane], wo510l = a4[576 + lane];
    float4 wo511m = a4[640 + lane], wo511l = a4[704 + lane];

    const float4 d4 = make_float4(0.f, 0.f, 0.f, 0.f);

    WSet A, B;
    ld_set(A, tape + 0 * TS, lane);     // group 0
    ld_set(B, tape + 1 * TS, lane);     // group 1

    float ls_sum = 0.f;

    // ---- step 0 (extra h=510) ----
    WAITVM(16);                          // A resident; B may fly
    stepC<0, 1>(0, lane, A, a0m, a0l, a1m, a1l, Rm, Rl, yv, xv, bmv, blv, ls_sum,
                e510mA, e510mB, e510lA, e510lB, wo510m, wo510l);
    ld_set(A, tape + 2 * TS, lane);

    // ---- step 1 (extra h=511) ----
    WAITVM(16);
    stepC<0, 2>(1, lane, B, a0m, a0l, a1m, a1l, Rm, Rl, yv, xv, bmv, blv, ls_sum,
                e511mA, e511mB, e511lA, e511lB, wo511m, wo511l);
    ld_set(B, tape + 3 * TS, lane);

#define PAIR_BODY(Q, i, t)                                                    \
    {                                                                         \
        int gA = (i) + 2 > 254 ? 254 : (i) + 2;                               \
        int gB = (i) + 3 > 254 ? 254 : (i) + 3;                               \
        WAITVM(16);                                                           \
        stepC<Q, 0>((t), lane, A, a0m, a0l, a1m, a1l, Rm, Rl, yv,             \
                    xv, bmv, blv, ls_sum, d4, d4, d4, d4, d4, d4);            \
        ld_set(A, tape + (size_t)gA * TS, lane);                              \
        WAITVM(16);                                                           \
        stepC<Q, 0>((t) + 1, lane, B, a0m, a0l, a1m, a1l, Rm, Rl, yv,         \
                    xv, bmv, blv, ls_sum, d4, d4, d4, d4, d4, d4);            \
        ld_set(B, tape + (size_t)gB * TS, lane);                              \
    }

    #pragma unroll 1
    for (int i = 2; i < 64; i += 2)    PAIR_BODY(0, i, i)
    #pragma unroll 1
    for (int i = 64; i < 128; i += 2)  PAIR_BODY(1, i, i - 64)
    #pragma unroll 1
    for (int i = 128; i < 192; i += 2) PAIR_BODY(2, i, i - 128)
    #pragma unroll 1
    for (int i = 192; i < 254; i += 2) PAIR_BODY(3, i, i - 192)
#undef PAIR_BODY

    // ---- step 254 (A = group 254) ----
    WAITVM(16);
    stepC<3, 0>(62, lane, A, a0m, a0l, a1m, a1l, Rm, Rl, yv, xv, bmv, blv, ls_sum,
                d4, d4, d4, d4, d4, d4);

    // ---- step 255: output only ----
    {
        float mu = rlf(Rm[3], 63) + rlf(bmv[3], 63);
        float ls = 0.5f * (rlf(Rl[3], 63) + rlf(blv[3], 63));
        ls_sum += ls;
        float v = __fdividef(rlf(xv[3], 63) - mu, __expf(ls) + 1e-12f);
        yv[3] = (lane == 63) ? v : yv[3];
    }

    #pragma unroll
    for (int r = 0; r < 4; ++r) out[row * DD + 64 * r + lane] = yv[r];
    if (lane == 0) out[BB * DD + row] = ls_sum;
}

extern "C" void kernel_launch(void* const* d_in, const int* in_sizes, int n_in,
                              void* d_out, int out_size, void* d_ws, size_t ws_size,
                              hipStream_t stream) {
    const float* x     = (const float*)d_in[0];
    const float* mu_W0 = (const float*)d_in[1];
    const float* mu_b0 = (const float*)d_in[2];
    const float* mu_W1 = (const float*)d_in[3];
    const float* mu_b1 = (const float*)d_in[4];
    const float* mu_Wo = (const float*)d_in[5];
    const float* mu_bo = (const float*)d_in[6];
    const float* lv_W0 = (const float*)d_in[7];
    const float* lv_b0 = (const float*)d_in[8];
    const float* lv_W1 = (const float*)d_in[9];
    const float* lv_b1 = (const float*)d_in[10];
    const float* lv_Wo = (const float*)d_in[11];
    const float* lv_bo = (const float*)d_in[12];

    float* tape = (float*)d_ws;   // 4 MiB

    prep<<<512, 256, 0, stream>>>(mu_W0, lv_W0, mu_W1, lv_W1, mu_Wo, lv_Wo, tape);
    made_main<<<BB, 128, 0, stream>>>(x, mu_b0, mu_b1, mu_bo,
                                      lv_b0, lv_b1, lv_bo, tape, (float*)d_out);
}